// Round 1
// baseline (1016.337 us; speedup 1.0000x reference)
//
#include <hip/hip_runtime.h>
#include <hip/hip_bf16.h>

// Problem constants
constexpr int TT = 4096;   // tokens
constexpr int HH = 2048;   // hidden
constexpr int II = 2048;   // intermediate
constexpr int EE = 16;     // experts
constexpr int KTOP = 4;    // top-k

typedef __attribute__((ext_vector_type(4))) float f4;
typedef __attribute__((ext_vector_type(8))) short s8;

__device__ __forceinline__ short f2bf(float f) {
    union { __hip_bfloat16 b; short s; } u;
    u.b = __float2bfloat16(f);
    return u.s;
}
__device__ __forceinline__ float bf2f(short s) {
    union { unsigned u; float f; } v;
    v.u = ((unsigned)(unsigned short)s) << 16;
    return v.f;
}

// ---------------------------------------------------------------------------
// Kernel 1: RMSNorm -> t_bf16. Also zeroes expert counters (block 0).
// ---------------------------------------------------------------------------
__global__ void k_rmsnorm(const float* __restrict__ x, const float* __restrict__ gamma,
                          short* __restrict__ t16, int* __restrict__ cnt) {
    const int row = blockIdx.x;
    const int tid = threadIdx.x;
    if (row == 0 && tid < EE) cnt[tid] = 0;
    const f4* xr = (const f4*)(x + (size_t)row * HH);
    f4 v0 = xr[tid * 2], v1 = xr[tid * 2 + 1];
    float ss = 0.f;
#pragma unroll
    for (int i = 0; i < 4; i++) { ss += v0[i] * v0[i]; ss += v1[i] * v1[i]; }
#pragma unroll
    for (int m = 32; m >= 1; m >>= 1) ss += __shfl_xor(ss, m);
    __shared__ float red[4];
    const int wid = tid >> 6, lane = tid & 63;
    if (lane == 0) red[wid] = ss;
    __syncthreads();
    const float tot = red[0] + red[1] + red[2] + red[3];
    const float rs = rsqrtf(tot * (1.f / HH) + 1e-6f);
    const f4* gr = (const f4*)gamma;
    f4 g0 = gr[tid * 2], g1 = gr[tid * 2 + 1];
    s8 o;
#pragma unroll
    for (int i = 0; i < 4; i++) {
        o[i]     = f2bf(v0[i] * rs * g0[i]);
        o[4 + i] = f2bf(v1[i] * rs * g1[i]);
    }
    *(s8*)(t16 + (size_t)row * HH + tid * 8) = o;
}

// ---------------------------------------------------------------------------
// Kernel 2: Router. One wave per token, fp32. Builds per-expert token lists.
// ---------------------------------------------------------------------------
__global__ void k_router(const float* __restrict__ x, const float* __restrict__ gamma,
                         const float* __restrict__ wg, const float* __restrict__ bg,
                         int* __restrict__ cnt, int* __restrict__ lst,
                         float* __restrict__ lwt) {
    const int lane = threadIdx.x & 63;
    const int tok = blockIdx.x * 4 + (threadIdx.x >> 6);
    const float* xr = x + (size_t)tok * HH;
    float t[32];
    float ss = 0.f;
#pragma unroll
    for (int j = 0; j < 32; j++) { float v = xr[lane + 64 * j]; t[j] = v; ss += v * v; }
#pragma unroll
    for (int m = 32; m >= 1; m >>= 1) ss += __shfl_xor(ss, m);
    const float rs = rsqrtf(ss * (1.f / HH) + 1e-6f);
#pragma unroll
    for (int j = 0; j < 32; j++) t[j] *= rs * gamma[lane + 64 * j];

    float logit[EE];
#pragma unroll
    for (int e = 0; e < EE; e++) {
        const float* wrow = wg + (size_t)e * HH;
        float a = 0.f;
#pragma unroll
        for (int j = 0; j < 32; j++) a += t[j] * wrow[lane + 64 * j];
#pragma unroll
        for (int m = 32; m >= 1; m >>= 1) a += __shfl_xor(a, m);
        logit[e] = a + bg[e];
    }
    // top-4 (ties -> lower index, matching lax.top_k)
    unsigned chosen = 0u;
    int sel[KTOP]; float sv[KTOP];
#pragma unroll
    for (int k = 0; k < KTOP; k++) {
        float best = -1e30f; int bi = 0;
#pragma unroll
        for (int e = 0; e < EE; e++) {
            bool take = (!((chosen >> e) & 1u)) && (logit[e] > best);
            if (take) { best = logit[e]; bi = e; }
        }
        chosen |= 1u << bi; sel[k] = bi; sv[k] = best;
    }
    const float lmax = sv[0];
    float s = 0.f;
#pragma unroll
    for (int k = 0; k < KTOP; k++) { sv[k] = expf(sv[k] - lmax); s += sv[k]; }
    const float inv = 1.f / s;
    if (lane == 0) {
#pragma unroll
        for (int k = 0; k < KTOP; k++) {
            int e = sel[k];
            int p = atomicAdd(&cnt[e], 1);
            lst[e * TT + p] = tok * KTOP + k;   // packed token*4+slot
            lwt[e * TT + p] = sv[k] * inv;
        }
    }
}

// ---------------------------------------------------------------------------
// Grouped GEMM (gate/up): h[pk] = t16[tok] @ W[e]^T.  128x128 tile, BK=64.
// A gathered via token list; B fp32 -> bf16 on the fly. XOR-swizzled LDS.
// ---------------------------------------------------------------------------
__global__ __launch_bounds__(256) void k_gemm_ffn(
        const short* __restrict__ t16, const float* __restrict__ w,
        short* __restrict__ hout, const int* __restrict__ cnt,
        const int* __restrict__ lst) {
    const int e = blockIdx.z;
    const int Me = cnt[e];
    const int m0 = blockIdx.y * 128;
    if (m0 >= Me) return;
    const int n0 = blockIdx.x * 128;
    const float* we = w + (size_t)e * II * HH;   // [N=I][K=H] row-major (B^T layout)

    __shared__ char lA[16384];
    __shared__ char lB[16384];
    __shared__ int s_tok[128];

    const int tid = threadIdx.x;
    if (tid < 128) {
        int m = m0 + tid;
        s_tok[tid] = (m < Me) ? lst[e * TT + m] : 0;
    }
    __syncthreads();

    const int lane = tid & 63, wid = tid >> 6;
    const int wr = wid >> 1, wc = wid & 1;

    f4 acc[4][4];
    const f4 zero = {0.f, 0.f, 0.f, 0.f};
#pragma unroll
    for (int i = 0; i < 4; i++)
#pragma unroll
        for (int j = 0; j < 4; j++) acc[i][j] = zero;

    // staging geometry: thread covers rows rbase+32j at k-chunk kc (8 elems)
    const int rbase = tid >> 3;
    const int kc = (tid & 7) * 8;
    const int lb0 = rbase * 128 + ((kc * 2) ^ ((rbase & 7) << 4));
    int tokrow[4];
#pragma unroll
    for (int j = 0; j < 4; j++) tokrow[j] = s_tok[rbase + 32 * j] >> 2;

    for (int kt = 0; kt < HH / 64; ++kt) {
        __syncthreads();
        // stage A (gathered bf16 rows)
#pragma unroll
        for (int j = 0; j < 4; j++) {
            s8 av = *(const s8*)(t16 + (size_t)tokrow[j] * HH + kt * 64 + kc);
            *(s8*)(lA + lb0 + 4096 * j) = av;
        }
        // stage B (fp32 -> bf16)
#pragma unroll
        for (int j = 0; j < 4; j++) {
            const float* gp = we + (size_t)(n0 + rbase + 32 * j) * HH + kt * 64 + kc;
            f4 b0 = *(const f4*)gp;
            f4 b1 = *(const f4*)(gp + 4);
            s8 bv;
#pragma unroll
            for (int i = 0; i < 4; i++) { bv[i] = f2bf(b0[i]); bv[4 + i] = f2bf(b1[i]); }
            *(s8*)(lB + lb0 + 4096 * j) = bv;
        }
        __syncthreads();
#pragma unroll
        for (int kk = 0; kk < 2; ++kk) {
            s8 af[4], bfr[4];
#pragma unroll
            for (int mf = 0; mf < 4; mf++) {
                int r = wr * 64 + mf * 16 + (lane & 15);
                int byte = r * 128 + (((kk * 64) + ((lane >> 4) << 4)) ^ ((r & 7) << 4));
                af[mf] = *(const s8*)(lA + byte);
            }
#pragma unroll
            for (int nf = 0; nf < 4; nf++) {
                int r = wc * 64 + nf * 16 + (lane & 15);
                int byte = r * 128 + (((kk * 64) + ((lane >> 4) << 4)) ^ ((r & 7) << 4));
                bfr[nf] = *(const s8*)(lB + byte);
            }
#pragma unroll
            for (int mf = 0; mf < 4; mf++)
#pragma unroll
                for (int nf = 0; nf < 4; nf++)
                    acc[mf][nf] = __builtin_amdgcn_mfma_f32_16x16x32_bf16(
                        af[mf], bfr[nf], acc[mf][nf], 0, 0, 0);
        }
    }
    // epilogue: C/D layout col=lane&15, row=(lane>>4)*4+reg
#pragma unroll
    for (int mf = 0; mf < 4; mf++) {
#pragma unroll
        for (int j = 0; j < 4; j++) {
            int rl = wr * 64 + mf * 16 + ((lane >> 4) << 2) + j;
            int m = m0 + rl;
            if (m < Me) {
                int pk = s_tok[rl];
                size_t orow = (size_t)pk * II;
#pragma unroll
                for (int nf = 0; nf < 4; nf++) {
                    int ncol = n0 + wc * 64 + nf * 16 + (lane & 15);
                    hout[orow + ncol] = f2bf(acc[mf][nf][j]);
                }
            }
        }
    }
}

// ---------------------------------------------------------------------------
// Kernel: h = silu(h1) * h3 (in place into h1)
// ---------------------------------------------------------------------------
__global__ void k_silu(short* __restrict__ h1, const short* __restrict__ h3) {
    size_t i = ((size_t)blockIdx.x * 256 + threadIdx.x) * 8;
    s8 g = *(const s8*)(h1 + i);
    s8 u = *(const s8*)(h3 + i);
    s8 o;
#pragma unroll
    for (int j = 0; j < 8; j++) {
        float gv = bf2f(g[j]), uv = bf2f(u[j]);
        float sv = gv / (1.f + expf(-gv));
        o[j] = f2bf(sv * uv);
    }
    *(s8*)(h1 + i) = o;
}

// ---------------------------------------------------------------------------
// Grouped GEMM (down): buf2[pk] = (h[pk] @ W2[e]^T) * weight
// ---------------------------------------------------------------------------
__global__ __launch_bounds__(256) void k_gemm_down(
        const short* __restrict__ h, const float* __restrict__ w2,
        float* __restrict__ buf2, const int* __restrict__ cnt,
        const int* __restrict__ lst, const float* __restrict__ lwt) {
    const int e = blockIdx.z;
    const int Me = cnt[e];
    const int m0 = blockIdx.y * 128;
    if (m0 >= Me) return;
    const int n0 = blockIdx.x * 128;
    const float* we = w2 + (size_t)e * HH * II;  // [N=H][K=I] row-major

    __shared__ char lA[16384];
    __shared__ char lB[16384];
    __shared__ int s_tok[128];
    __shared__ float s_wgt[128];

    const int tid = threadIdx.x;
    if (tid < 128) {
        int m = m0 + tid;
        bool v = (m < Me);
        s_tok[tid] = v ? lst[e * TT + m] : 0;
        s_wgt[tid] = v ? lwt[e * TT + m] : 0.f;
    }
    __syncthreads();

    const int lane = tid & 63, wid = tid >> 6;
    const int wr = wid >> 1, wc = wid & 1;

    f4 acc[4][4];
    const f4 zero = {0.f, 0.f, 0.f, 0.f};
#pragma unroll
    for (int i = 0; i < 4; i++)
#pragma unroll
        for (int j = 0; j < 4; j++) acc[i][j] = zero;

    const int rbase = tid >> 3;
    const int kc = (tid & 7) * 8;
    const int lb0 = rbase * 128 + ((kc * 2) ^ ((rbase & 7) << 4));
    int arow[4];
#pragma unroll
    for (int j = 0; j < 4; j++) arow[j] = s_tok[rbase + 32 * j];  // pk is the h-row

    for (int kt = 0; kt < II / 64; ++kt) {
        __syncthreads();
#pragma unroll
        for (int j = 0; j < 4; j++) {
            s8 av = *(const s8*)(h + (size_t)arow[j] * II + kt * 64 + kc);
            *(s8*)(lA + lb0 + 4096 * j) = av;
        }
#pragma unroll
        for (int j = 0; j < 4; j++) {
            const float* gp = we + (size_t)(n0 + rbase + 32 * j) * II + kt * 64 + kc;
            f4 b0 = *(const f4*)gp;
            f4 b1 = *(const f4*)(gp + 4);
            s8 bv;
#pragma unroll
            for (int i = 0; i < 4; i++) { bv[i] = f2bf(b0[i]); bv[4 + i] = f2bf(b1[i]); }
            *(s8*)(lB + lb0 + 4096 * j) = bv;
        }
        __syncthreads();
#pragma unroll
        for (int kk = 0; kk < 2; ++kk) {
            s8 af[4], bfr[4];
#pragma unroll
            for (int mf = 0; mf < 4; mf++) {
                int r = wr * 64 + mf * 16 + (lane & 15);
                int byte = r * 128 + (((kk * 64) + ((lane >> 4) << 4)) ^ ((r & 7) << 4));
                af[mf] = *(const s8*)(lA + byte);
            }
#pragma unroll
            for (int nf = 0; nf < 4; nf++) {
                int r = wc * 64 + nf * 16 + (lane & 15);
                int byte = r * 128 + (((kk * 64) + ((lane >> 4) << 4)) ^ ((r & 7) << 4));
                bfr[nf] = *(const s8*)(lB + byte);
            }
#pragma unroll
            for (int mf = 0; mf < 4; mf++)
#pragma unroll
                for (int nf = 0; nf < 4; nf++)
                    acc[mf][nf] = __builtin_amdgcn_mfma_f32_16x16x32_bf16(
                        af[mf], bfr[nf], acc[mf][nf], 0, 0, 0);
        }
    }
#pragma unroll
    for (int mf = 0; mf < 4; mf++) {
#pragma unroll
        for (int j = 0; j < 4; j++) {
            int rl = wr * 64 + mf * 16 + ((lane >> 4) << 2) + j;
            int m = m0 + rl;
            if (m < Me) {
                int pk = s_tok[rl];
                float wgt = s_wgt[rl];
                size_t orow = (size_t)pk * HH;
#pragma unroll
                for (int nf = 0; nf < 4; nf++) {
                    int ncol = n0 + wc * 64 + nf * 16 + (lane & 15);
                    buf2[orow + ncol] = acc[mf][nf][j] * wgt;
                }
            }
        }
    }
}

// ---------------------------------------------------------------------------
// Final: out = x + sum_k buf2[token*4+k]
// ---------------------------------------------------------------------------
__global__ void k_final(const float* __restrict__ x, const float* __restrict__ buf2,
                        float* __restrict__ out) {
    size_t i4 = (size_t)blockIdx.x * 256 + threadIdx.x;   // f4 index into [T][H]
    size_t tok = i4 / (HH / 4);
    size_t c4 = i4 % (HH / 4);
    f4 r = ((const f4*)x)[i4];
#pragma unroll
    for (int k = 0; k < KTOP; k++) {
        f4 b = ((const f4*)buf2)[(tok * KTOP + k) * (HH / 4) + c4];
        r += b;
    }
    ((f4*)out)[i4] = r;
}

// ---------------------------------------------------------------------------
extern "C" void kernel_launch(void* const* d_in, const int* in_sizes, int n_in,
                              void* d_out, int out_size, void* d_ws, size_t ws_size,
                              hipStream_t stream) {
    const float* x     = (const float*)d_in[0];
    const float* gamma = (const float*)d_in[1];
    const float* wg    = (const float*)d_in[2];
    const float* bg    = (const float*)d_in[3];
    const float* w1    = (const float*)d_in[4];
    const float* w3    = (const float*)d_in[5];
    const float* w2    = (const float*)d_in[6];
    float* out = (float*)d_out;

    char* ws = (char*)d_ws;
    size_t off = 0;
    short* t16 = (short*)(ws + off); off += (size_t)TT * HH * 2;        // 16 MB
    short* h1  = (short*)(ws + off); off += (size_t)TT * KTOP * II * 2; // 64 MB
    short* h3  = (short*)(ws + off); off += (size_t)TT * KTOP * II * 2; // 64 MB
    float* buf2 = (float*)(ws + off); off += (size_t)TT * KTOP * HH * 4;// 128 MB
    int* cnt   = (int*)(ws + off); off += 256;
    int* lst   = (int*)(ws + off); off += (size_t)EE * TT * 4;
    float* lwt = (float*)(ws + off); off += (size_t)EE * TT * 4;

    k_rmsnorm<<<TT, 256, 0, stream>>>(x, gamma, t16, cnt);
    k_router<<<TT / 4, 256, 0, stream>>>(x, gamma, wg, bg, cnt, lst, lwt);

    dim3 g1(II / 128, TT / 128, EE);
    k_gemm_ffn<<<g1, 256, 0, stream>>>(t16, w1, h1, cnt, lst);
    k_gemm_ffn<<<g1, 256, 0, stream>>>(t16, w3, h3, cnt, lst);

    k_silu<<<(TT * KTOP * II / 8) / 256, 256, 0, stream>>>(h1, h3);

    dim3 g2(HH / 128, TT / 128, EE);
    k_gemm_down<<<g2, 256, 0, stream>>>(h1, w2, buf2, cnt, lst, lwt);

    k_final<<<(TT * HH / 4) / 256, 256, 0, stream>>>(x, buf2, out);
}